// Round 2
// baseline (445.009 us; speedup 1.0000x reference)
//
#include <hip/hip_runtime.h>
#include <hip/hip_bf16.h>

// B=16, S=2048, D=128 causal attention, pre-scale threshold:
//   A = Q@T^T; A = (A>0.3 ? A : 0); causal -2^32; /sqrt(128); softmax; @V
// fp32 in/out, bf16 MFMA internal. Fixed-max softmax (m=0) => partial
// (oacc, sum-l) accumulators are ADDITIVE => arbitrary K-splits combine.
//
// V3: occupancy push. R1 showed V1(decoupled)==V2(lockstep) at 2 waves/SIMD,
// nothing saturated => latency-bound. VGPR(112) caps at 4 waves/SIMD, reached
// only by 4-wave blocks * <=40KB LDS * 4 blocks/CU => grid 1024:
//   pair pi work = 33 tiles (light qt=pi: L=pi+1 tiles; heavy qt=31-pi: 32-pi),
//   enumerated e in [0,33) (light first), chunked [0,9,17,25,33) over 4 blocks.
// Cross-block combine: fixed-max partials are additive. Non-last contributors
// store (oacc,l) to ws; last (atomic ticket + release/acquire done counter,
// spin is deadlock-free without any residency assumption) sums+normalizes.
// Contributor counts: n_light = 1+(L>=10) (1 => direct store), n_heavy = 4-(L>=9).

#define S_LEN 2048
#define D_DIM 128
#define BQ 64
#define BK 64
#define THRESH 0.3f
#define EXP2C 0.12751742f   // (1/sqrt(128)) * log2(e):  exp(s/sqrt(d)) = 2^(s*EXP2C)

typedef __bf16 bf16x8 __attribute__((ext_vector_type(8)));
typedef float f32x4 __attribute__((ext_vector_type(4)));

// -------- V transpose + downcast: V[b][s][d] fp32 -> Vt[b][d][s] bf16 --------
// Also zeroes the 1024 protocol counters (stream order => visible to fa_kernel).
__global__ void vt_kernel(const float* __restrict__ V, __bf16* __restrict__ Vt,
                          int* __restrict__ ctrs) {
    __shared__ float tile[64][65];
    int bid = blockIdx.x;
    int tid = threadIdx.x;                     // 256 threads
    if (bid == 0) {
        #pragma unroll
        for (int i = 0; i < 4; ++i) ctrs[tid * 4 + i] = 0;
    }
    int b  = bid >> 6;
    int t2 = bid & 63;
    int s0 = (t2 >> 1) * 64;
    int d0 = (t2 & 1) * 64;
    #pragma unroll
    for (int it = 0; it < 2; ++it) {
        int row = it * 32 + (tid >> 3);
        int c   = (tid & 7) * 8;
        const float* p = V + ((size_t)b * S_LEN + s0 + row) * D_DIM + d0 + c;
        *(f32x4*)(&tile[row][c])     = *(const f32x4*)p;
        *(f32x4*)(&tile[row][c + 4]) = *(const f32x4*)(p + 4);
    }
    __syncthreads();
    #pragma unroll
    for (int it = 0; it < 2; ++it) {
        int dr = it * 32 + (tid >> 3);
        int c  = (tid & 7) * 8;
        bf16x8 w;
        #pragma unroll
        for (int j = 0; j < 8; ++j) w[j] = (__bf16)tile[c + j][dr];
        *(bf16x8*)(Vt + ((size_t)b * D_DIM + d0 + dr) * S_LEN + s0 + c) = w;
    }
}

// ---------------- Flash attention, causal + threshold, fixed-max ----------------
// 256 threads = 4 waves; LDS exactly 40960 B => 4 blocks/CU (16 waves/CU):
//   [    0, 16384)  Tt: 64 rows x 128 bf16 (256B/row, XOR-swizzled)
//   [16384, 32768)  Vl: 128 rows x 64 bf16 (128B/row, XOR-swizzled)
//   [32768, 40960)  Pl: 4 waves x (16 rows x 64 bf16, 128B/row, swizzled)
__global__ __launch_bounds__(256, 4)
void fa_kernel(const float* __restrict__ Q, const float* __restrict__ T,
               const __bf16* __restrict__ Vt, float* __restrict__ O,
               float* __restrict__ pO, float* __restrict__ pL,
               int* __restrict__ cnt, int* __restrict__ done) {
    __shared__ __align__(16) unsigned char smem[40960];

    const int bid = blockIdx.x;                 // b fastest => batch data clusters per XCD L2
    const int b   = bid & 15;
    const int pi  = (bid >> 4) & 15;            // pair index
    const int c   = bid >> 8;                   // chunk 0..3
    const int qtH = 31 - pi;
    const int L   = pi + 1;                     // light tile count

    const int tid  = threadIdx.x;
    const int lane = tid & 63;
    const int wv   = tid >> 6;                  // wave 0..3
    const int col  = lane & 15;
    const int quad = lane >> 4;

    unsigned char* Tt = smem;
    unsigned char* Vl = smem + 16384;
    unsigned char* Pw = smem + 32768 + wv * 2048;
    int* tkp = (int*)(smem + 32768);            // ticket broadcast (Pl reuse, barrier-fenced)

    // ---- Q fragments (16 rows x D=128), reloadable (block may switch q-tile) ----
    bf16x8 qf[4];
    auto loadQ = [&](int qt) {
        const float* qptr = Q + ((size_t)b * S_LEN + qt * BQ + wv * 16 + col) * D_DIM + quad * 8;
        #pragma unroll
        for (int kk = 0; kk < 4; ++kk) {
            f32x4 a = *(const f32x4*)(qptr + kk * 32);
            f32x4 d = *(const f32x4*)(qptr + kk * 32 + 4);
            #pragma unroll
            for (int j = 0; j < 4; ++j) { qf[kk][j] = (__bf16)a[j]; qf[kk][4 + j] = (__bf16)d[j]; }
        }
    };

    f32x4 oacc[8];
    float lsum[4];
    auto resetAcc = [&]() {
        #pragma unroll
        for (int dt = 0; dt < 8; ++dt) oacc[dt] = {0.f, 0.f, 0.f, 0.f};
        #pragma unroll
        for (int r = 0; r < 4; ++r) lsum[r] = 0.f;
    };

    // ---- staging: global -> regs -> swizzled LDS ----
    f32x4 tr[8]; bf16x8 vr[4];
    auto loadTiles = [&](int k0) {
        #pragma unroll
        for (int it = 0; it < 4; ++it) {
            int flat = it * 2048 + tid * 8;
            int row = flat >> 7, cc = flat & 127;
            const float* p = T + ((size_t)b * S_LEN + k0 + row) * D_DIM + cc;
            tr[2 * it]     = *(const f32x4*)p;
            tr[2 * it + 1] = *(const f32x4*)(p + 4);
        }
        #pragma unroll
        for (int it = 0; it < 4; ++it) {
            int flat = it * 2048 + tid * 8;
            int d = flat >> 6, kk2 = flat & 63;
            vr[it] = *(const bf16x8*)(Vt + ((size_t)b * D_DIM + d) * S_LEN + k0 + kk2);
        }
    };
    auto storeTiles = [&]() {
        #pragma unroll
        for (int it = 0; it < 4; ++it) {
            int flat = it * 2048 + tid * 8;
            int row = flat >> 7, cc = flat & 127;
            bf16x8 w;
            #pragma unroll
            for (int j = 0; j < 4; ++j) {
                w[j]     = (__bf16)tr[2 * it][j];
                w[4 + j] = (__bf16)tr[2 * it + 1][j];
            }
            *(bf16x8*)(Tt + row * 256 + ((cc * 2) ^ ((row & 7) << 4))) = w;
        }
        #pragma unroll
        for (int it = 0; it < 4; ++it) {
            int flat = it * 2048 + tid * 8;
            int d = flat >> 6, kk2 = flat & 63;
            *(bf16x8*)(Vl + d * 128 + ((kk2 * 2) ^ ((d & 7) << 4))) = vr[it];
        }
    };

    // ---- one K-tile: QK^T -> threshold/exp -> P relayout -> PV ----
    auto computeTile = [&](bool diag) {
        f32x4 sacc[4];
        #pragma unroll
        for (int t = 0; t < 4; ++t) {
            sacc[t] = {0.f, 0.f, 0.f, 0.f};
            #pragma unroll
            for (int kk = 0; kk < 4; ++kk) {
                int row = t * 16 + col;
                bf16x8 bf = *(const bf16x8*)(Tt + row * 256 + ((kk * 64 + quad * 16) ^ ((row & 7) << 4)));
                sacc[t] = __builtin_amdgcn_mfma_f32_16x16x32_bf16(qf[kk], bf, sacc[t], 0, 0, 0);
            }
        }
        float p[4][4];
        #pragma unroll
        for (int t = 0; t < 4; ++t)
            #pragma unroll
            for (int r = 0; r < 4; ++r) {
                float s = sacc[t][r];
                float e = exp2f(s * EXP2C);
                float w = (s > THRESH) ? e : 1.0f;
                if (diag && (t * 16 + col > wv * 16 + quad * 4 + r)) w = 0.0f;
                p[t][r] = w;
            }
        #pragma unroll
        for (int r = 0; r < 4; ++r)
            lsum[r] += (p[0][r] + p[1][r]) + (p[2][r] + p[3][r]);

        // C-layout -> LDS -> A-layout (per-wave scratch, swizzled)
        #pragma unroll
        for (int t = 0; t < 4; ++t)
            #pragma unroll
            for (int r = 0; r < 4; ++r) {
                int row = quad * 4 + r;
                *(__bf16*)(Pw + row * 128 + (((t * 16 + col) * 2) ^ ((row & 7) << 4))) = (__bf16)p[t][r];
            }
        asm volatile("s_waitcnt lgkmcnt(0)" ::: "memory");  // wave-local RAW on Pw

        #pragma unroll
        for (int ks = 0; ks < 2; ++ks) {
            bf16x8 af = *(const bf16x8*)(Pw + col * 128 + ((ks * 64 + quad * 16) ^ ((col & 7) << 4)));
            #pragma unroll
            for (int dt = 0; dt < 8; ++dt) {
                int row = dt * 16 + col;
                bf16x8 bf = *(const bf16x8*)(Vl + row * 128 + ((ks * 64 + quad * 16) ^ ((row & 7) << 4)));
                oacc[dt] = __builtin_amdgcn_mfma_f32_16x16x32_bf16(af, bf, oacc[dt], 0, 0, 0);
            }
        }
    };

    auto runSeg = [&](int qt, int k0t, int nt) {
        loadQ(qt); resetAcc();
        loadTiles(k0t * BK);
        storeTiles();
        __syncthreads();
        for (int s = 0; s < nt; ++s) {
            if (s + 1 < nt) loadTiles((k0t + s + 1) * BK);
            computeTile(k0t + s == qt);
            __syncthreads();
            if (s + 1 < nt) { storeTiles(); __syncthreads(); }
        }
    };

    auto storeO = [&](int qt, const float inv[4]) {
        float* optr = O + ((size_t)b * S_LEN + qt * BQ + wv * 16) * D_DIM;
        #pragma unroll
        for (int dt = 0; dt < 8; ++dt)
            #pragma unroll
            for (int r = 0; r < 4; ++r)
                optr[(quad * 4 + r) * D_DIM + dt * 16 + col] = oacc[dt][r] * inv[r];
    };

    // ---- flush one finished q-tile segment (direct or via ws combine) ----
    auto flushTarget = [&](int qt, int tgt, int n) {
        float lred[4];
        #pragma unroll
        for (int r = 0; r < 4; ++r) {
            float l = lsum[r];
            l += __shfl_xor(l, 1); l += __shfl_xor(l, 2);
            l += __shfl_xor(l, 4); l += __shfl_xor(l, 8);
            lred[r] = l;
        }
        if (n == 1) {
            float inv[4];
            #pragma unroll
            for (int r = 0; r < 4; ++r) inv[r] = 1.0f / lred[r];
            storeO(qt, inv);
            return;
        }
        const int pairid = b * 16 + pi;
        const int cidx   = pairid * 2 + tgt;
        __syncthreads();
        if (tid == 0)
            *tkp = __hip_atomic_fetch_add(&cnt[cidx], 1, __ATOMIC_RELAXED, __HIP_MEMORY_SCOPE_AGENT);
        __syncthreads();
        int t = *tkp;
        __syncthreads();
        if (t < n - 1) {
            // store partial: light uses slot 3, heavy slots 0..2 (by ticket)
            int slot = (tgt == 0) ? 3 : t;
            float* po = pO + ((size_t)pairid * 4 + slot) * (64 * 128);
            float* pl = pL + ((size_t)pairid * 4 + slot) * 64;
            #pragma unroll
            for (int dt = 0; dt < 8; ++dt)
                #pragma unroll
                for (int r = 0; r < 4; ++r)
                    po[(wv * 16 + quad * 4 + r) * 128 + dt * 16 + col] = oacc[dt][r];
            if (col == 0) {
                #pragma unroll
                for (int r = 0; r < 4; ++r) pl[wv * 16 + quad * 4 + r] = lred[r];
            }
            __threadfence();
            __syncthreads();
            if (tid == 0)
                __hip_atomic_fetch_add(&done[cidx], 1, __ATOMIC_RELEASE, __HIP_MEMORY_SCOPE_AGENT);
        } else {
            if (tid == 0) {
                while (__hip_atomic_load(&done[cidx], __ATOMIC_ACQUIRE, __HIP_MEMORY_SCOPE_AGENT) < n - 1)
                    __builtin_amdgcn_s_sleep(8);
            }
            __syncthreads();
            __threadfence();
            for (int s = 0; s < n - 1; ++s) {
                int slot = (tgt == 0) ? 3 : s;
                const float* po = pO + ((size_t)pairid * 4 + slot) * (64 * 128);
                const float* pl = pL + ((size_t)pairid * 4 + slot) * 64;
                #pragma unroll
                for (int dt = 0; dt < 8; ++dt)
                    #pragma unroll
                    for (int r = 0; r < 4; ++r)
                        oacc[dt][r] += po[(wv * 16 + quad * 4 + r) * 128 + dt * 16 + col];
                #pragma unroll
                for (int r = 0; r < 4; ++r) lred[r] += pl[wv * 16 + quad * 4 + r];
            }
            float inv[4];
            #pragma unroll
            for (int r = 0; r < 4; ++r) inv[r] = 1.0f / lred[r];
            storeO(qt, inv);
        }
    };

    // ---- chunk schedule: e in [lo,hi) of the 33-tile pair enumeration ----
    const int Btab[5] = {0, 9, 17, 25, 33};
    const int lo = Btab[c], hi = Btab[c + 1];

    int lend = L < hi ? L : hi;                  // light portion end
    if (lo < lend) {
        runSeg(pi, lo, lend - lo);
        flushTarget(pi, 0, 1 + (L >= 10));
    }
    int hstart = L > lo ? L : lo;                // heavy portion start
    if (hstart < hi) {
        runSeg(qtH, hstart - L, hi - hstart);
        flushTarget(qtH, 1, 4 - (L >= 9));
    }
}

extern "C" void kernel_launch(void* const* d_in, const int* in_sizes, int n_in,
                              void* d_out, int out_size, void* d_ws, size_t ws_size,
                              hipStream_t stream) {
    const float* Q = (const float*)d_in[0];
    const float* T = (const float*)d_in[1];
    const float* V = (const float*)d_in[2];
    float* O = (float*)d_out;

    // ws layout: Vt 8MB | partial O 32MB | partial l 256KB | counters 4KB  (~40.3MB)
    unsigned char* ws = (unsigned char*)d_ws;
    __bf16* Vt = (__bf16*)ws;                                    // 16*128*2048*2
    float* pO  = (float*)(ws + 8388608);                         // 256 pairs * 4 slots * 64*128 f32
    float* pL  = (float*)(ws + 8388608 + 33554432);              // 256 * 4 * 64 f32
    int*  ctrs = (int*)(ws + 8388608 + 33554432 + 262144);       // cnt[512] ++ done[512]
    int*  cnt  = ctrs;
    int*  done = ctrs + 512;

    vt_kernel<<<16 * 64, 256, 0, stream>>>(V, Vt, ctrs);
    fa_kernel<<<16 * 16 * 4, 256, 0, stream>>>(Q, T, Vt, O, pO, pL, cnt, done);
}

// Round 3
// 132.395 us; speedup vs baseline: 3.3612x; 3.3612x over previous
//
#include <hip/hip_runtime.h>
#include <hip/hip_bf16.h>

// B=16, S=2048, D=128 causal attention, pre-scale threshold:
//   A = Q@T^T; A = (A>0.3 ? A : 0); causal -2^32; /sqrt(128); softmax; @V
// fp32 in/out, bf16 MFMA internal. Fixed-max softmax (m=0; post-threshold
// logits in [0,~9]) => partial (oacc, sum-l) accumulators are ADDITIVE.
//
// V4 (recovery from V3 spill disaster; mechanism = shorten per-tile path):
//  * T pre-converted to bf16 (prep) => fa stages T and V with
//    global_load_lds (16B DMA): no staging VGPRs (V2 held 48), no cvt,
//    no ds_write. LDS XOR-swizzle preserved by pre-swizzling the per-lane
//    GLOBAL source address (LDS side of gload_lds is linear, m104/m173).
//  * Double-buffered tiles + counted s_waitcnt vmcnt(8): next tile's 8 DMA
//    loads stay in flight across the barrier (T3/T4). vmcnt(8) is always
//    safe: older epilogue stores just drain early.
//  * Uniform grid 512 = (b, pair, chunk): chunk0 = light(L)+heavy[0,17-L),
//    chunk1 = heavy[17-L,33-L). Light: single contributor -> direct store.
//    Heavy: exactly 2 contributors -> per-slot partial store (no atomics,
//    no zeroing), summed by nrm_kernel. Epilogue tiny => no spill risk.
//  * __launch_bounds__(256,2): V3 proved 4 waves/SIMD forces spills.

#define S_LEN 2048
#define D_DIM 128
#define BQ 64
#define BK 64
#define THRESH 0.3f
#define SCALE 0.08838834764831845f   // 1/sqrt(128)

typedef __bf16 bf16x8 __attribute__((ext_vector_type(8)));
typedef float f32x4 __attribute__((ext_vector_type(4)));

#define GLD16(g, l)                                                         \
    __builtin_amdgcn_global_load_lds(                                       \
        (const __attribute__((address_space(1))) unsigned int*)(g),         \
        (__attribute__((address_space(3))) unsigned int*)(l), 16, 0, 0)

// ---- prep: Tb[b][s][d] bf16 downcast; Vt[b][d][s] bf16 transpose ----
__global__ void prep_kernel(const float* __restrict__ V, const float* __restrict__ T,
                            __bf16* __restrict__ Vt, __bf16* __restrict__ Tb) {
    __shared__ float tile[64][65];
    int bid = blockIdx.x;                      // 1024 blocks
    int tid = threadIdx.x;                     // 256 threads
    int b  = bid >> 6;
    int t2 = bid & 63;

    // T downcast: rows [t2*32, t2*32+32) of batch b; 16 f32 per thread.
    {
        int flat = tid * 16;
        int r = flat >> 7, cc = flat & 127;
        const float* p = T + ((size_t)b * S_LEN + t2 * 32 + r) * D_DIM + cc;
        __bf16* q = Tb + ((size_t)b * S_LEN + t2 * 32 + r) * D_DIM + cc;
        bf16x8 w0, w1;
        f32x4 a0 = *(const f32x4*)p,       a1 = *(const f32x4*)(p + 4);
        f32x4 a2 = *(const f32x4*)(p + 8), a3 = *(const f32x4*)(p + 12);
        #pragma unroll
        for (int j = 0; j < 4; ++j) {
            w0[j] = (__bf16)a0[j]; w0[4 + j] = (__bf16)a1[j];
            w1[j] = (__bf16)a2[j]; w1[4 + j] = (__bf16)a3[j];
        }
        *(bf16x8*)q = w0;
        *(bf16x8*)(q + 8) = w1;
    }

    // V transpose tile: s0 x d0 64x64
    int s0 = (t2 >> 1) * 64;
    int d0 = (t2 & 1) * 64;
    #pragma unroll
    for (int it = 0; it < 2; ++it) {
        int row = it * 32 + (tid >> 3);
        int c   = (tid & 7) * 8;
        const float* p = V + ((size_t)b * S_LEN + s0 + row) * D_DIM + d0 + c;
        *(f32x4*)(&tile[row][c])     = *(const f32x4*)p;
        *(f32x4*)(&tile[row][c + 4]) = *(const f32x4*)(p + 4);
    }
    __syncthreads();
    #pragma unroll
    for (int it = 0; it < 2; ++it) {
        int dr = it * 32 + (tid >> 3);
        int c  = (tid & 7) * 8;
        bf16x8 w;
        #pragma unroll
        for (int j = 0; j < 8; ++j) w[j] = (__bf16)tile[c + j][dr];
        *(bf16x8*)(Vt + ((size_t)b * D_DIM + d0 + dr) * S_LEN + s0 + c) = w;
    }
}

// ---------------- Flash attention, causal + threshold, fixed-max ----------------
// 256 threads = 4 waves. LDS 73728 B => 2 blocks/CU:
//   [    0, 32768)  Tt dbuf: 2 x (64 rows x 256B), XOR-swizzled via source
//   [32768, 65536)  Vl dbuf: 2 x (128 rows x 128B), XOR-swizzled via source
//   [65536, 73728)  Pl: 4 waves x 2KB (16 rows x 128B, swizzled)
__global__ __launch_bounds__(256, 2)
void fa_kernel(const float* __restrict__ Q, const __bf16* __restrict__ Tb,
               const __bf16* __restrict__ Vt, float* __restrict__ O,
               float* __restrict__ pO, float* __restrict__ pL) {
    __shared__ __align__(16) unsigned char smem[73728];

    const int bid = blockIdx.x;          // 512: b fastest => 2 batches per XCD (L2-fit)
    const int b   = bid & 15;
    const int pi  = (bid >> 4) & 15;     // pair index
    const int c   = bid >> 8;            // chunk 0/1
    const int qtH = 31 - pi;
    const int L   = pi + 1;              // light tile count (1..16)

    const int tid  = threadIdx.x;
    const int lane = tid & 63;
    const int wv   = tid >> 6;
    const int col  = lane & 15;
    const int quad = lane >> 4;

    unsigned char* Pw = smem + 65536 + wv * 2048;

    const __bf16* TbB = Tb + (size_t)b * S_LEN * D_DIM;
    const __bf16* VtB = Vt + (size_t)b * D_DIM * S_LEN;

    // per-thread swizzled source offsets (elements) for the 4+4 DMA issues
    int toff[4], voff[4];
    #pragma unroll
    for (int i = 0; i < 4; ++i) {
        int trw = wv * 16 + i * 4 + (lane >> 4);
        toff[i] = trw * 128 + (((lane & 15) ^ (trw & 7)) << 3);
        int drw = wv * 32 + i * 8 + (lane >> 3);
        voff[i] = drw * 2048 + (((lane & 7) ^ (drw & 7)) << 3);
    }

    // issue one tile's 8 DMA loads into buffer buf (k0 = key index)
    auto issueTile = [&](int k0, int buf) {
        const __bf16* ts = TbB + (size_t)k0 * D_DIM;
        const __bf16* vs = VtB + k0;
        unsigned char* lt = smem + buf * 16384 + wv * 4096;
        unsigned char* lv = smem + 32768 + buf * 16384 + wv * 4096;
        #pragma unroll
        for (int i = 0; i < 4; ++i) GLD16(ts + toff[i], lt + i * 1024);
        #pragma unroll
        for (int i = 0; i < 4; ++i) GLD16(vs + voff[i], lv + i * 1024);
    };

    bf16x8 qf[4];
    auto loadQ = [&](int qt) {
        const float* qptr = Q + ((size_t)b * S_LEN + qt * BQ + wv * 16 + col) * D_DIM + quad * 8;
        #pragma unroll
        for (int kk = 0; kk < 4; ++kk) {
            f32x4 a = *(const f32x4*)(qptr + kk * 32);
            f32x4 d = *(const f32x4*)(qptr + kk * 32 + 4);
            #pragma unroll
            for (int j = 0; j < 4; ++j) { qf[kk][j] = (__bf16)a[j]; qf[kk][4 + j] = (__bf16)d[j]; }
        }
    };

    f32x4 oacc[8];
    float lsum[4];

    auto computeTile = [&](int buf, bool diag) {
        unsigned char* Tt = smem + buf * 16384;
        unsigned char* Vl = smem + 32768 + buf * 16384;
        f32x4 sacc[4];
        __builtin_amdgcn_s_setprio(1);
        #pragma unroll
        for (int t = 0; t < 4; ++t) {
            sacc[t] = {0.f, 0.f, 0.f, 0.f};
            #pragma unroll
            for (int kk = 0; kk < 4; ++kk) {
                int row = t * 16 + col;
                bf16x8 bf = *(const bf16x8*)(Tt + row * 256 + ((kk * 64 + quad * 16) ^ ((row & 7) << 4)));
                sacc[t] = __builtin_amdgcn_mfma_f32_16x16x32_bf16(qf[kk], bf, sacc[t], 0, 0, 0);
            }
        }
        __builtin_amdgcn_s_setprio(0);
        float p[4][4];
        #pragma unroll
        for (int t = 0; t < 4; ++t)
            #pragma unroll
            for (int r = 0; r < 4; ++r) {
                float s = sacc[t][r];
                float e = __expf(s * SCALE);
                float w = (s > THRESH) ? e : 1.0f;
                if (diag && (t * 16 + col > wv * 16 + quad * 4 + r)) w = 0.0f;
                p[t][r] = w;
            }
        #pragma unroll
        for (int r = 0; r < 4; ++r)
            lsum[r] += (p[0][r] + p[1][r]) + (p[2][r] + p[3][r]);

        // C-layout -> LDS -> A-layout (per-wave scratch, swizzled)
        #pragma unroll
        for (int t = 0; t < 4; ++t)
            #pragma unroll
            for (int r = 0; r < 4; ++r) {
                int row = quad * 4 + r;
                *(__bf16*)(Pw + row * 128 + (((t * 16 + col) * 2) ^ ((row & 7) << 4))) = (__bf16)p[t][r];
            }
        asm volatile("s_waitcnt lgkmcnt(0)" ::: "memory");  // wave-local RAW on Pw

        __builtin_amdgcn_s_setprio(1);
        #pragma unroll
        for (int ks = 0; ks < 2; ++ks) {
            bf16x8 af = *(const bf16x8*)(Pw + col * 128 + ((ks * 64 + quad * 16) ^ ((col & 7) << 4)));
            #pragma unroll
            for (int dt = 0; dt < 8; ++dt) {
                int row = dt * 16 + col;
                bf16x8 bf = *(const bf16x8*)(Vl + row * 128 + ((ks * 64 + quad * 16) ^ ((row & 7) << 4)));
                oacc[dt] = __builtin_amdgcn_mfma_f32_16x16x32_bf16(af, bf, oacc[dt], 0, 0, 0);
            }
        }
        __builtin_amdgcn_s_setprio(0);
    };

    auto finishSeg = [&](int qt) {
        float lred[4];
        #pragma unroll
        for (int r = 0; r < 4; ++r) {
            float l = lsum[r];
            l += __shfl_xor(l, 1); l += __shfl_xor(l, 2);
            l += __shfl_xor(l, 4); l += __shfl_xor(l, 8);
            lred[r] = l;
        }
        if (qt < 16) {                      // light: sole contributor -> direct
            float* optr = O + ((size_t)b * S_LEN + qt * BQ + wv * 16) * D_DIM;
            #pragma unroll
            for (int dt = 0; dt < 8; ++dt)
                #pragma unroll
                for (int r = 0; r < 4; ++r)
                    optr[(quad * 4 + r) * D_DIM + dt * 16 + col] = oacc[dt][r] * (1.0f / lred[r]);
        } else {                            // heavy: per-chunk slot, summed by nrm
            size_t slot = (size_t)((b * 16 + pi) * 2 + c);
            float* po = pO + slot * (64 * 128);
            float* pl = pL + slot * 64;
            #pragma unroll
            for (int dt = 0; dt < 8; ++dt)
                #pragma unroll
                for (int r = 0; r < 4; ++r)
                    po[(wv * 16 + quad * 4 + r) * 128 + dt * 16 + col] = oacc[dt][r];
            if (col == 0) {
                #pragma unroll
                for (int r = 0; r < 4; ++r) pl[wv * 16 + quad * 4 + r] = lred[r];
            }
        }
    };

    const int nseg = (c == 0) ? 2 : 1;
    for (int is = 0; is < nseg; ++is) {
        int qt, k0t, nt;
        if (c == 0) {
            if (is == 0) { qt = pi;  k0t = 0;      nt = L;      }
            else         { qt = qtH; k0t = 0;      nt = 17 - L; }
        } else           { qt = qtH; k0t = 17 - L; nt = 16;     }

        loadQ(qt);
        #pragma unroll
        for (int dt = 0; dt < 8; ++dt) oacc[dt] = {0.f, 0.f, 0.f, 0.f};
        #pragma unroll
        for (int r = 0; r < 4; ++r) lsum[r] = 0.f;

        issueTile(k0t * BK, 0);
        for (int s = 0; s < nt; ++s) {
            if (s + 1 < nt) {
                issueTile((k0t + s + 1) * BK, (s + 1) & 1);
                asm volatile("s_waitcnt vmcnt(8)" ::: "memory");  // tile s done; s+1 in flight
            } else {
                asm volatile("s_waitcnt vmcnt(0)" ::: "memory");
            }
            __builtin_amdgcn_s_barrier();
            computeTile(s & 1, k0t + s == qt);
            __builtin_amdgcn_s_barrier();
        }
        finishSeg(qt);
    }
}

// ---- nrm: heavy q-tiles only: O = (pO[slot0]+pO[slot1]) / (pL0+pL1) ----
__global__ void nrm_kernel(const float* __restrict__ pO, const float* __restrict__ pL,
                           float* __restrict__ O) {
    int gid  = blockIdx.x * 256 + threadIdx.x;   // 512 blocks -> 131072 threads
    int flat = gid * 16;                          // 16*16*64*128 = 2.097M f32
    int pr   = flat >> 13;                        // (b*16+pi)
    int rl   = (flat >> 7) & 63;
    int cc   = flat & 127;
    int b = pr >> 4, pi = pr & 15;
    const float* p0 = pO + ((size_t)pr * 2)     * 8192 + rl * 128 + cc;
    const float* p1 = pO + ((size_t)pr * 2 + 1) * 8192 + rl * 128 + cc;
    float inv = 1.0f / (pL[(pr * 2) * 64 + rl] + pL[(pr * 2 + 1) * 64 + rl]);
    float* op = O + ((size_t)b * S_LEN + (31 - pi) * 64 + rl) * D_DIM + cc;
    #pragma unroll
    for (int j = 0; j < 4; ++j) {
        f32x4 a = *(const f32x4*)(p0 + j * 4);
        f32x4 d = *(const f32x4*)(p1 + j * 4);
        f32x4 o;
        #pragma unroll
        for (int r = 0; r < 4; ++r) o[r] = (a[r] + d[r]) * inv;
        *(f32x4*)(op + j * 4) = o;
    }
}

extern "C" void kernel_launch(void* const* d_in, const int* in_sizes, int n_in,
                              void* d_out, int out_size, void* d_ws, size_t ws_size,
                              hipStream_t stream) {
    const float* Q = (const float*)d_in[0];
    const float* T = (const float*)d_in[1];
    const float* V = (const float*)d_in[2];
    float* O = (float*)d_out;

    // ws: Vt 8MB | Tb 8MB | pO 16.78MB | pL 128KB   (~33.7MB)
    unsigned char* ws = (unsigned char*)d_ws;
    __bf16* Vt = (__bf16*)ws;
    __bf16* Tb = (__bf16*)(ws + 8388608);
    float*  pO = (float*)(ws + 16777216);
    float*  pL = (float*)(ws + 16777216 + 16777216);

    prep_kernel<<<1024, 256, 0, stream>>>(V, T, Vt, Tb);
    fa_kernel<<<512, 256, 0, stream>>>(Q, Tb, Vt, O, pO, pL);
    nrm_kernel<<<512, 256, 0, stream>>>(pO, pL, O);
}